// Round 9
// baseline (2521.856 us; speedup 1.0000x reference)
//
#include <hip/hip_runtime.h>

#define H 51
#define NROW 612          // 3 matrices x 204 gate-rows
#define WREG 32           // weights k=0..31 live in registers
#define WSTR 20           // LDS row stride in floats (k=32..51, k=51 is zero pad)

__device__ __forceinline__ float rl_(float v, int lane) {
    return __builtin_bit_cast(float, __builtin_amdgcn_readlane(__builtin_bit_cast(int, v), lane));
}
template<int CTRL>
__device__ __forceinline__ float qb_(float v) {   // quad_perm broadcast (DPP, VALU pipe)
    return __builtin_bit_cast(float, __builtin_amdgcn_update_dpp(
        0, __builtin_bit_cast(int, v), CTRL, 0xf, 0xf, true));
}

// act = A * rcp(1 + exp2(m2*x)) + B   (sigmoid: m2=-log2e,A=1,B=0 ; tanh: m2=2log2e,A=-2,B=1)
__device__ __forceinline__ float act_(float x, float m2, float A, float B) {
    const float e = __builtin_amdgcn_exp2f(m2 * x);
    const float r = __builtin_amdgcn_rcpf(1.f + e);
    return fmaf(A, r, B);
}
__device__ __forceinline__ float tanh_(float c) {
    const float e = __builtin_amdgcn_exp2f(2.885390082f * c);
    const float r = __builtin_amdgcn_rcpf(1.f + e);
    return fmaf(-2.f, r, 1.f);
}

#define FOR32(M) \
 M(0) M(1) M(2) M(3) M(4) M(5) M(6) M(7) M(8) M(9) \
 M(10) M(11) M(12) M(13) M(14) M(15) M(16) M(17) M(18) M(19) \
 M(20) M(21) M(22) M(23) M(24) M(25) M(26) M(27) M(28) M(29) M(30) M(31)

// M(k, k%4): round-robin accumulators, k ascending (same fma order as rounds 5-8)
#define FOR32_RR(M) \
 M(0,0) M(1,1) M(2,2) M(3,3) M(4,0) M(5,1) M(6,2) M(7,3) \
 M(8,0) M(9,1) M(10,2) M(11,3) M(12,0) M(13,1) M(14,2) M(15,3) \
 M(16,0) M(17,1) M(18,2) M(19,3) M(20,0) M(21,1) M(22,2) M(23,3) \
 M(24,0) M(25,1) M(26,2) M(27,3) M(28,0) M(29,1) M(30,2) M(31,3)

__global__ __launch_bounds__(768)    // no min-waves: let the backend target its
                                     // default high occupancy (64-VGPR budget) and
                                     // make our ~62-reg live set fit UNDER it
void lstm_seq_kernel(const float* __restrict__ x,
                     const float* __restrict__ Wih1, const float* __restrict__ Whh1,
                     const float* __restrict__ bih1, const float* __restrict__ bhh1,
                     const float* __restrict__ Wih2, const float* __restrict__ Whh2,
                     const float* __restrict__ bih2, const float* __restrict__ bhh2,
                     const float* __restrict__ fcw, const float* __restrict__ fcb,
                     float* __restrict__ out, int T, int future)
{
    const int b   = blockIdx.x;
    const int tid = threadIdx.x;
    const int l   = tid & 63;          // lane
    const int w   = tid >> 6;          // wave 0..11
    const int grp = w >> 2;            // 0: Whh1+act1+c1 | 1: Whh2 partial | 2: Wih2+act2+c2+fc
    const int j   = w & 3;             // wave within group
    const int uq  = l >> 2;            // unit-within-wave 0..15 (13 valid)
    const int g   = l & 3;             // gate 0:i 1:f 2:g 3:o
    const int u   = 13 * j + uq;       // unit 0..50 (wave j=3 has 12 valid)
    const bool act_lane = (uq < 13) && (u < H);
    const bool g0lane   = act_lane && (g == 0);
    const int row = act_lane ? (g * H + u) : 0;     // clamped: inactive lanes use row 0

    __shared__ __align__(16) float wlds[NROW * WSTR];   // weight tail slice, 49 KB
    __shared__ float h1s[2][64];                // double-buffered h1 (pad zeros)
    __shared__ float h2s[2][64];
    __shared__ float hh2buf[220];               // Whh2.h2 partial, idx = 52*j + l
    __shared__ __align__(16) float fcp[4];      // per-wave fc partial sums

    // ---- stage weight tail (k=32..50) into LDS, k=51 slot zeroed ----
    for (int i = tid; i < NROW * WSTR; i += 768) {
        const int r  = i / WSTR;
        const int kk = i % WSTR;
        float v = 0.f;
        if (kk < WSTR - 1) {
            const int m  = r / 204;
            const int rr = r % 204;
            const float* W = (m == 0) ? Whh1 : ((m == 1) ? Whh2 : Wih2);
            v = W[rr * H + WREG + kk];
        }
        wlds[i] = v;
    }
    if (tid < 64) { h1s[0][tid] = 0.f; h1s[1][tid] = 0.f;
                    h2s[0][tid] = 0.f; h2s[1][tid] = 0.f; }
    if (tid < 4) fcp[tid] = 0.f;

    // ---- register slice: weights k=0..31 as named scalars ----
    const float* Wm = (grp == 0) ? Whh1 : ((grp == 1) ? Whh2 : Wih2);
    const int rb = row * H;
    #define DECLW(k) float wt_##k = Wm[rb + k];
    FOR32(DECLW)

    const float* wrow = &wlds[(grp * 204 + row) * WSTR];   // this lane's LDS tail row

    // per-row constants
    const float wx1   = (grp == 0 && act_lane) ? Wih1[row] : 0.f;
    const float bias1 = (grp == 0 && act_lane) ? (bih1[row] + bhh1[row]) : 0.f;
    const float bias2 = (grp == 2 && act_lane) ? (bih2[row] + bhh2[row]) : 0.f;
    const float fcu   = (grp == 2 && g0lane) ? fcw[u] : 0.f;
    const float fcb_l = fcb[0];

    // activation constants per gate lane (grp 0 and 2)
    const float m2A = (g == 2) ? 2.885390082f : -1.442695041f;
    const float Aa  = act_lane ? ((g == 2) ? -2.f : 1.f) : 0.f;
    const float Ba  = (act_lane && g == 2) ? 1.f : 0.f;

    float cc = 0.f;                    // c1 (grp0) / c2 (grp2), quad-replicated
    float xt_pre = (grp == 0) ? x[(size_t)b * T] : 0.f;   // software prefetch of x[t]

    __syncthreads();

    // MAC macros (preprocessor-scoped; each branch provides hv / a0..a3 / q0..q4)
    #define MR(k, jj) a##jj = fmaf(rl_(hv, k), wt_##k, a##jj);
    #define MAC4(Q, KB) \
        a0 = fmaf(rl_(hv, KB + 0), Q.x, a0); \
        a1 = fmaf(rl_(hv, KB + 1), Q.y, a1); \
        a2 = fmaf(rl_(hv, KB + 2), Q.z, a2); \
        a3 = fmaf(rl_(hv, KB + 3), Q.w, a3);
    #define DOT_TAIL() \
        const float4* wf = (const float4*)wrow; \
        const float4 q0 = wf[0], q1 = wf[1], q2 = wf[2], q3 = wf[3], q4 = wf[4]; \
        MAC4(q0, 32) MAC4(q1, 36) MAC4(q2, 40) MAC4(q3, 44) MAC4(q4, 48)

    const int TT = T + future;
    for (int t = 0; t < TT; ++t) {
        const int p = t & 1, q = p ^ 1;

        // ---- out(t-1) from fc partials (all threads compute o; tid0 stores) ----
        float o = 0.f;
        if (t > 0) {
            const float4 f = *(const float4*)fcp;
            o = (f.x + f.y) + (f.z + f.w) + fcb_l;
            if (tid == 0) out[(size_t)b * TT + (t - 1)] = o;
        }

        // ================= phase B =================
        if (grp == 0) {
            // full layer 1: pre1 -> gates (DPP quad) -> c1 -> h1(t)
            const float xt = (t < T) ? xt_pre : o;
            if (t + 1 < T) xt_pre = x[(size_t)b * T + t + 1];   // prefetch next x
            const float hv = h1s[q][l];
            float a0 = 0.f, a1 = 0.f, a2 = 0.f, a3 = 0.f;
            FOR32_RR(MR)
            DOT_TAIL()
            const float pre1 = bias1 + fmaf(wx1, xt, (a0 + a1) + (a2 + a3));
            const float a = act_(pre1, m2A, Aa, Ba);
            const float si = qb_<0x00>(a);
            const float sf = qb_<0x55>(a);
            const float tg = qb_<0xAA>(a);
            const float so = qb_<0xFF>(a);
            cc = fmaf(sf, cc, si * tg);
            const float h1n = so * tanh_(cc);
            if (g0lane) h1s[p][u] = h1n;
        } else if (grp == 1) {
            // hh2 = Whh2[row,:] . h2(t-1)
            const float hv = h2s[q][l];
            float a0 = 0.f, a1 = 0.f, a2 = 0.f, a3 = 0.f;
            FOR32_RR(MR)
            DOT_TAIL()
            if (act_lane) hh2buf[52 * j + l] = (a0 + a1) + (a2 + a3);
        }
        __syncthreads();                       // barrier 1: h1(t), hh2buf visible

        // ================= phase C =================
        if (grp == 2) {
            const float hv = h1s[p][l];
            float a0 = 0.f, a1 = 0.f, a2 = 0.f, a3 = 0.f;
            FOR32_RR(MR)
            DOT_TAIL()
            const float hh2 = act_lane ? hh2buf[52 * j + l] : 0.f;
            const float pre2 = bias2 + hh2 + ((a0 + a1) + (a2 + a3));
            const float a = act_(pre2, m2A, Aa, Ba);
            const float si = qb_<0x00>(a);
            const float sf = qb_<0x55>(a);
            const float tg = qb_<0xAA>(a);
            const float so = qb_<0xFF>(a);
            cc = fmaf(sf, cc, si * tg);
            const float h2n = so * tanh_(cc);
            if (g0lane) h2s[p][u] = h2n;

            // fc partial for this wave's 13 units
            float pv = g0lane ? h2n * fcu : 0.f;
            pv += __shfl_xor(pv, 4, 64);
            pv += __shfl_xor(pv, 8, 64);
            pv += __shfl_xor(pv, 16, 64);
            pv += __shfl_xor(pv, 32, 64);
            if (l == 0) fcp[j] = pv;
        }
        __syncthreads();                       // barrier 2: h2(t), fcp visible
    }

    if (tid == 0) {
        const float4 f = *(const float4*)fcp;
        out[(size_t)b * TT + (TT - 1)] = (f.x + f.y) + (f.z + f.w) + fcb_l;
    }
}

extern "C" void kernel_launch(void* const* d_in, const int* in_sizes, int n_in,
                              void* d_out, int out_size, void* d_ws, size_t ws_size,
                              hipStream_t stream) {
    const float* x    = (const float*)d_in[0];
    const float* Wih1 = (const float*)d_in[1];
    const float* Whh1 = (const float*)d_in[2];
    const float* bih1 = (const float*)d_in[3];
    const float* bhh1 = (const float*)d_in[4];
    const float* Wih2 = (const float*)d_in[5];
    const float* Whh2 = (const float*)d_in[6];
    const float* bih2 = (const float*)d_in[7];
    const float* bhh2 = (const float*)d_in[8];
    const float* fcw  = (const float*)d_in[9];
    const float* fcb  = (const float*)d_in[10];
    float* out = (float*)d_out;

    const int B  = 256;                 // fixed by setup (H=51 hardcoded)
    const int T  = in_sizes[0] / B;     // 2048
    const int TT = out_size / B;        // T + future
    const int future = TT - T;

    hipLaunchKernelGGL(lstm_seq_kernel, dim3(B), dim3(768), 0, stream,
                       x, Wih1, Whh1, bih1, bhh1, Wih2, Whh2, bih2, bhh2,
                       fcw, fcb, out, T, future);
}

// Round 10
// 2307.250 us; speedup vs baseline: 1.0930x; 1.0930x over previous
//
#include <hip/hip_runtime.h>

#define H 51

__device__ __forceinline__ float rl_(float v, int lane) {
    return __builtin_bit_cast(float, __builtin_amdgcn_readlane(__builtin_bit_cast(int, v), lane));
}
template<int CTRL>
__device__ __forceinline__ float qb_(float v) {   // quad_perm broadcast (DPP, VALU pipe)
    return __builtin_bit_cast(float, __builtin_amdgcn_update_dpp(
        0, __builtin_bit_cast(int, v), CTRL, 0xf, 0xf, true));
}

// act = A * rcp(1 + exp2(m2*x)) + B   (sigmoid: m2=-log2e,A=1,B=0 ; tanh: m2=2log2e,A=-2,B=1)
__device__ __forceinline__ float act_(float x, float m2, float A, float B) {
    const float e = __builtin_amdgcn_exp2f(m2 * x);
    const float r = __builtin_amdgcn_rcpf(1.f + e);
    return fmaf(A, r, B);
}
__device__ __forceinline__ float tanh_(float c) {
    const float e = __builtin_amdgcn_exp2f(2.885390082f * c);
    const float r = __builtin_amdgcn_rcpf(1.f + e);
    return fmaf(-2.f, r, 1.f);
}

// ---- apply M(k) for k = 0..50 ----
#define FOR51(M) \
 M(0) M(1) M(2) M(3) M(4) M(5) M(6) M(7) M(8) M(9) \
 M(10) M(11) M(12) M(13) M(14) M(15) M(16) M(17) M(18) M(19) \
 M(20) M(21) M(22) M(23) M(24) M(25) M(26) M(27) M(28) M(29) \
 M(30) M(31) M(32) M(33) M(34) M(35) M(36) M(37) M(38) M(39) \
 M(40) M(41) M(42) M(43) M(44) M(45) M(46) M(47) M(48) M(49) M(50)

// ---- apply M(k, k%4) for k = 0..50 (round-robin accumulators) ----
#define FOR51_RR(M) \
 M(0,0) M(1,1) M(2,2) M(3,3) M(4,0) M(5,1) M(6,2) M(7,3) \
 M(8,0) M(9,1) M(10,2) M(11,3) M(12,0) M(13,1) M(14,2) M(15,3) \
 M(16,0) M(17,1) M(18,2) M(19,3) M(20,0) M(21,1) M(22,2) M(23,3) \
 M(24,0) M(25,1) M(26,2) M(27,3) M(28,0) M(29,1) M(30,2) M(31,3) \
 M(32,0) M(33,1) M(34,2) M(35,3) M(36,0) M(37,1) M(38,2) M(39,3) \
 M(40,0) M(41,1) M(42,2) M(43,3) M(44,0) M(45,1) M(46,2) M(47,3) \
 M(48,0) M(49,1) M(50,2)

__global__ __launch_bounds__(768)
__attribute__((amdgpu_waves_per_eu(3, 3)))   // grid is 1 block/CU: 12 waves = 3/EU
                                             // is the true occupancy; VGPR budget 170
void lstm_seq_kernel(const float* __restrict__ x,
                     const float* __restrict__ Wih1, const float* __restrict__ Whh1,
                     const float* __restrict__ bih1, const float* __restrict__ bhh1,
                     const float* __restrict__ Wih2, const float* __restrict__ Whh2,
                     const float* __restrict__ bih2, const float* __restrict__ bhh2,
                     const float* __restrict__ fcw, const float* __restrict__ fcb,
                     float* __restrict__ out, int T, int future)
{
    const int b   = blockIdx.x;
    const int tid = threadIdx.x;
    const int l   = tid & 63;          // lane
    const int w   = tid >> 6;          // wave 0..11
    const int grp = w >> 2;            // 0: Whh1+act1+c1 | 1: Whh2 partial | 2: Wih2+act2+c2+fc
    const int j   = w & 3;             // wave within group
    const int uq  = l >> 2;            // unit-within-wave 0..15 (13 valid)
    const int g   = l & 3;             // gate 0:i 1:f 2:g 3:o
    const int u   = 13 * j + uq;       // unit 0..50 (wave j=3 has 12 valid)
    const bool act_lane = (uq < 13) && (u < H);
    const bool g0lane   = act_lane && (g == 0);
    const int row = act_lane ? (g * H + u) : 0;     // clamped: inactive lanes read row 0

    extern __shared__ float xld[];              // [T] this batch row of x
    __shared__ float h1s[2][64];                // double-buffered h1 (pad zeros)
    __shared__ float h2s[2][64];
    __shared__ float hh2buf[220];               // Whh2.h2 partial, idx = 52*j + l
    __shared__ __align__(16) float fcp[4];      // per-wave fc partial sums

    for (int i = tid; i < T; i += 768) xld[i] = x[(size_t)b * T + i];
    if (tid < 64) { h1s[0][tid] = 0.f; h1s[1][tid] = 0.f;
                    h2s[0][tid] = 0.f; h2s[1][tid] = 0.f; }
    if (tid < 4) fcp[tid] = 0.f;

    // per-lane weight row as 51 NAMED scalars (no array -> no SROA scratch).
    const float* Wm = (grp == 0) ? Whh1 : ((grp == 1) ? Whh2 : Wih2);
    const size_t rb = (size_t)row * H;
    #define DECLW(k) float wt_##k;
    FOR51(DECLW)
    #define LOADW(k) wt_##k = Wm[rb + k];
    FOR51(LOADW)

    // per-row constants
    const float wx1   = (grp == 0 && act_lane) ? Wih1[row] : 0.f;
    const float bias1 = (grp == 0 && act_lane) ? (bih1[row] + bhh1[row]) : 0.f;
    const float bias2 = (grp == 2 && act_lane) ? (bih2[row] + bhh2[row]) : 0.f;
    const float fcu   = (grp == 2 && g0lane) ? fcw[u] : 0.f;
    const float fcb_l = fcb[0];

    // activation constants per gate lane (grp 0 and 2)
    const float m2A = (g == 2) ? 2.885390082f : -1.442695041f;
    const float Aa  = act_lane ? ((g == 2) ? -2.f : 1.f) : 0.f;
    const float Ba  = (act_lane && g == 2) ? 1.f : 0.f;

    float cc = 0.f;                    // c1 (grp0) / c2 (grp2), quad-replicated
    __syncthreads();

    const int TT = T + future;
    for (int t = 0; t < TT; ++t) {
        const int p = t & 1, q = p ^ 1;

        // SINGLE multi-operand pin: at this point ALL 51 weights must occupy
        // VGPRs simultaneously (asm constraint), every iteration. Remat is
        // impossible (asm def); per-iteration spill would cost 102 scratch ops
        // -> the only cheap allocation is keeping them resident across the loop.
        asm volatile("" :
            "+v"(wt_0),  "+v"(wt_1),  "+v"(wt_2),  "+v"(wt_3),  "+v"(wt_4),
            "+v"(wt_5),  "+v"(wt_6),  "+v"(wt_7),  "+v"(wt_8),  "+v"(wt_9),
            "+v"(wt_10), "+v"(wt_11), "+v"(wt_12), "+v"(wt_13), "+v"(wt_14),
            "+v"(wt_15), "+v"(wt_16), "+v"(wt_17), "+v"(wt_18), "+v"(wt_19),
            "+v"(wt_20), "+v"(wt_21), "+v"(wt_22), "+v"(wt_23), "+v"(wt_24),
            "+v"(wt_25), "+v"(wt_26), "+v"(wt_27), "+v"(wt_28), "+v"(wt_29),
            "+v"(wt_30), "+v"(wt_31), "+v"(wt_32), "+v"(wt_33), "+v"(wt_34),
            "+v"(wt_35), "+v"(wt_36), "+v"(wt_37), "+v"(wt_38), "+v"(wt_39),
            "+v"(wt_40), "+v"(wt_41), "+v"(wt_42), "+v"(wt_43), "+v"(wt_44),
            "+v"(wt_45), "+v"(wt_46), "+v"(wt_47), "+v"(wt_48), "+v"(wt_49),
            "+v"(wt_50));

        // ---- out(t-1) from fc partials (all threads compute o; tid0 stores) ----
        float o = 0.f;
        if (t > 0) {
            const float4 f = *(const float4*)fcp;
            o = (f.x + f.y) + (f.z + f.w) + fcb_l;
            if (tid == 0) out[(size_t)b * TT + (t - 1)] = o;
        }

        // ================= phase B =================
        if (grp == 0) {
            // full layer 1: pre1 -> gates (DPP quad) -> c1 -> h1(t)
            const float xt = (t < T) ? xld[t] : o;
            const float hv = h1s[q][l];
            float a0 = 0.f, a1 = 0.f, a2 = 0.f, a3 = 0.f;
            #define MACB(k, jj) a##jj = fmaf(rl_(hv, k), wt_##k, a##jj);
            FOR51_RR(MACB)
            const float pre1 = bias1 + fmaf(wx1, xt, (a0 + a1) + (a2 + a3));
            const float a = act_(pre1, m2A, Aa, Ba);
            const float si = qb_<0x00>(a);
            const float sf = qb_<0x55>(a);
            const float tg = qb_<0xAA>(a);
            const float so = qb_<0xFF>(a);
            cc = fmaf(sf, cc, si * tg);
            const float h1n = so * tanh_(cc);
            if (g0lane) h1s[p][u] = h1n;
        } else if (grp == 1) {
            // hh2 = Whh2[row,:] . h2(t-1)
            const float hv = h2s[q][l];
            float a0 = 0.f, a1 = 0.f, a2 = 0.f, a3 = 0.f;
            FOR51_RR(MACB)
            if (act_lane) hh2buf[52 * j + l] = (a0 + a1) + (a2 + a3);
        }
        __syncthreads();                       // barrier 1: h1(t), hh2buf visible

        // ================= phase C =================
        if (grp == 2) {
            const float hv = h1s[p][l];
            float a0 = 0.f, a1 = 0.f, a2 = 0.f, a3 = 0.f;
            FOR51_RR(MACB)
            const float hh2 = act_lane ? hh2buf[52 * j + l] : 0.f;
            const float pre2 = bias2 + hh2 + ((a0 + a1) + (a2 + a3));
            const float a = act_(pre2, m2A, Aa, Ba);
            const float si = qb_<0x00>(a);
            const float sf = qb_<0x55>(a);
            const float tg = qb_<0xAA>(a);
            const float so = qb_<0xFF>(a);
            cc = fmaf(sf, cc, si * tg);
            const float h2n = so * tanh_(cc);
            if (g0lane) h2s[p][u] = h2n;

            // fc partial for this wave's 13 units
            float pv = g0lane ? h2n * fcu : 0.f;
            pv += __shfl_xor(pv, 4, 64);
            pv += __shfl_xor(pv, 8, 64);
            pv += __shfl_xor(pv, 16, 64);
            pv += __shfl_xor(pv, 32, 64);
            if (l == 0) fcp[j] = pv;
        }
        __syncthreads();                       // barrier 2: h2(t), fcp visible
    }

    if (tid == 0) {
        const float4 f = *(const float4*)fcp;
        out[(size_t)b * TT + (TT - 1)] = (f.x + f.y) + (f.z + f.w) + fcb_l;
    }
}

extern "C" void kernel_launch(void* const* d_in, const int* in_sizes, int n_in,
                              void* d_out, int out_size, void* d_ws, size_t ws_size,
                              hipStream_t stream) {
    const float* x    = (const float*)d_in[0];
    const float* Wih1 = (const float*)d_in[1];
    const float* Whh1 = (const float*)d_in[2];
    const float* bih1 = (const float*)d_in[3];
    const float* bhh1 = (const float*)d_in[4];
    const float* Wih2 = (const float*)d_in[5];
    const float* Whh2 = (const float*)d_in[6];
    const float* bih2 = (const float*)d_in[7];
    const float* bhh2 = (const float*)d_in[8];
    const float* fcw  = (const float*)d_in[9];
    const float* fcb  = (const float*)d_in[10];
    float* out = (float*)d_out;

    const int B  = 256;                 // fixed by setup (H=51 hardcoded)
    const int T  = in_sizes[0] / B;     // 2048
    const int TT = out_size / B;        // T + future
    const int future = TT - T;

    const size_t shmem = (size_t)T * sizeof(float);
    hipLaunchKernelGGL(lstm_seq_kernel, dim3(B), dim3(768), shmem, stream,
                       x, Wih1, Whh1, bih1, bhh1, Wih2, Whh2, bih2, bhh2,
                       fcw, fcb, out, T, future);
}